// Round 1
// baseline (951.660 us; speedup 1.0000x reference)
//
#include <hip/hip_runtime.h>
#include <hip/hip_bf16.h>

typedef __bf16 bf16_t;
typedef __bf16 bf16x4_t __attribute__((ext_vector_type(4)));
typedef __bf16 bf16x8_t __attribute__((ext_vector_type(8)));
typedef float f32x4_t __attribute__((ext_vector_type(4)));

typedef __attribute__((address_space(1))) void gvoid_t;
typedef __attribute__((address_space(3))) void svoid_t;

__device__ __forceinline__ void gload_lds16(const void* g, void* s) {
    // async global->LDS, 16B per lane; LDS dest = wave-uniform base + lane*16
    __builtin_amdgcn_global_load_lds((gvoid_t*)g, (svoid_t*)s, 16, 0, 0);
}

// ---------------------------------------------------------------------------
// m97-style GEMM: C[M,N] = scale * (A[M,K] @ Bt[N,K]^T) + bias
// 128x128 block tile, BK=32, 4 waves in 2x2, each wave 64x64 via 4x4 grid of
// 16x16x32 bf16 MFMAs. M%128==0, N%128==0, K%32==0 (all true here).
// ---------------------------------------------------------------------------
template <typename CT, bool BIAS>
__global__ __launch_bounds__(256, 2)
void gemm_bt(const bf16_t* __restrict__ A, const bf16_t* __restrict__ Bt,
             CT* __restrict__ C, const float* __restrict__ bias,
             int M, int N, int K, float scale,
             size_t sA, size_t sB, size_t sC)
{
    __shared__ bf16_t As[128 * 32];
    __shared__ bf16_t Bs[128 * 32];
    A  += (size_t)blockIdx.z * sA;
    Bt += (size_t)blockIdx.z * sB;
    C  += (size_t)blockIdx.z * sC;

    const int tid  = threadIdx.x;
    const int wave = tid >> 6;
    const int lane = tid & 63;
    const int m0 = blockIdx.y * 128;
    const int n0 = blockIdx.x * 128;

    // staging: chunk c = tid + 256*j (j=0,1); row = c>>2, kchunk = c&3 (8 elems)
    const int c0 = tid, c1 = tid + 256;
    const bf16_t* ag0 = A  + (size_t)(m0 + (c0 >> 2)) * K + (c0 & 3) * 8;
    const bf16_t* ag1 = A  + (size_t)(m0 + (c1 >> 2)) * K + (c1 & 3) * 8;
    const bf16_t* bg0 = Bt + (size_t)(n0 + (c0 >> 2)) * K + (c0 & 3) * 8;
    const bf16_t* bg1 = Bt + (size_t)(n0 + (c1 >> 2)) * K + (c1 & 3) * 8;
    bf16_t* asb0 = As + (size_t)(wave * 64) * 8;        // + lane*16B implied
    bf16_t* asb1 = As + (size_t)(wave * 64 + 256) * 8;
    bf16_t* bsb0 = Bs + (size_t)(wave * 64) * 8;
    bf16_t* bsb1 = Bs + (size_t)(wave * 64 + 256) * 8;

    const int fr = lane & 15;          // fragment row (m or n)
    const int fk = (lane >> 4) * 8;    // fragment k offset
    const int wm = (wave >> 1) * 64;
    const int wn = (wave & 1) * 64;

    f32x4_t acc[4][4];
#pragma unroll
    for (int i = 0; i < 4; ++i)
#pragma unroll
        for (int j = 0; j < 4; ++j)
            acc[i][j] = (f32x4_t){0.f, 0.f, 0.f, 0.f};

    for (int kt = 0; kt < K; kt += 32) {
        gload_lds16(ag0, asb0);
        gload_lds16(ag1, asb1);
        gload_lds16(bg0, bsb0);
        gload_lds16(bg1, bsb1);
        ag0 += 32; ag1 += 32; bg0 += 32; bg1 += 32;
        __builtin_amdgcn_s_waitcnt(0);   // drain vmcnt before barrier
        __syncthreads();

        bf16x8_t af[4], bf[4];
#pragma unroll
        for (int i = 0; i < 4; ++i)
            af[i] = *(const bf16x8_t*)&As[(wm + i * 16 + fr) * 32 + fk];
#pragma unroll
        for (int j = 0; j < 4; ++j)
            bf[j] = *(const bf16x8_t*)&Bs[(wn + j * 16 + fr) * 32 + fk];
#pragma unroll
        for (int i = 0; i < 4; ++i)
#pragma unroll
            for (int j = 0; j < 4; ++j)
                acc[i][j] = __builtin_amdgcn_mfma_f32_16x16x32_bf16(
                    af[i], bf[j], acc[i][j], 0, 0, 0);
        __syncthreads();   // protect LDS before next stage
    }

    // C/D layout: col = lane&15, row = (lane>>4)*4 + r   [m89/m91 verified]
#pragma unroll
    for (int j = 0; j < 4; ++j) {
        const int col = n0 + wn + j * 16 + fr;
        const float bv = BIAS ? bias[col] : 0.0f;
#pragma unroll
        for (int i = 0; i < 4; ++i) {
            const int row = m0 + wm + i * 16 + (lane >> 4) * 4;
            f32x4_t v = acc[i][j];
#pragma unroll
            for (int r = 0; r < 4; ++r) {
                float val = v[r] * scale + bv;
                C[(size_t)(row + r) * N + col] = (CT)val;
            }
        }
    }
}

// ---------------------------------------------------------------------------
// LayerNorm: one wave per row, D = NV*256 (NV float4 per lane). fp32 in,
// bf16 out.
// ---------------------------------------------------------------------------
template <int NV>
__global__ __launch_bounds__(256, 4)
void layernorm_k(const float* __restrict__ x, const float* __restrict__ g,
                 const float* __restrict__ b, bf16_t* __restrict__ y)
{
    const int D = NV * 256;
    const int wave = threadIdx.x >> 6, lane = threadIdx.x & 63;
    const size_t row = (size_t)blockIdx.x * 4 + wave;
    const float4* xr = (const float4*)(x + row * D);

    float4 v[NV];
    float s = 0.f, sq = 0.f;
#pragma unroll
    for (int i = 0; i < NV; ++i) {
        v[i] = xr[lane + 64 * i];
        s  += v[i].x + v[i].y + v[i].z + v[i].w;
        sq += v[i].x * v[i].x + v[i].y * v[i].y + v[i].z * v[i].z + v[i].w * v[i].w;
    }
#pragma unroll
    for (int m = 32; m; m >>= 1) {
        s  += __shfl_xor(s, m, 64);
        sq += __shfl_xor(sq, m, 64);
    }
    const float mean = s / D;
    const float rstd = rsqrtf(fmaxf(sq / D - mean * mean, 0.f) + 1e-5f);

#pragma unroll
    for (int i = 0; i < NV; ++i) {
        const int c4 = lane + 64 * i;
        float4 gg = ((const float4*)g)[c4];
        float4 bb = ((const float4*)b)[c4];
        bf16x4_t o;
        o[0] = (bf16_t)((v[i].x - mean) * rstd * gg.x + bb.x);
        o[1] = (bf16_t)((v[i].y - mean) * rstd * gg.y + bb.y);
        o[2] = (bf16_t)((v[i].z - mean) * rstd * gg.z + bb.z);
        o[3] = (bf16_t)((v[i].w - mean) * rstd * gg.w + bb.w);
        *(bf16x4_t*)(y + row * D + (size_t)c4 * 4) = o;
    }
}

// ---------------------------------------------------------------------------
// In-place row softmax over 2048 bf16 entries; one wave per row.
// ---------------------------------------------------------------------------
__global__ __launch_bounds__(256, 4)
void softmax_rows(bf16_t* __restrict__ a)
{
    const int wave = threadIdx.x >> 6, lane = threadIdx.x & 63;
    const size_t row = (size_t)blockIdx.x * 4 + wave;
    bf16_t* r = a + row * 2048;

    float v[32];
    float mx = -3.0e38f;
#pragma unroll
    for (int i = 0; i < 4; ++i) {
        bf16x8_t t = *(const bf16x8_t*)(r + (size_t)(lane + 64 * i) * 8);
#pragma unroll
        for (int j = 0; j < 8; ++j) {
            v[i * 8 + j] = (float)t[j];
            mx = fmaxf(mx, v[i * 8 + j]);
        }
    }
#pragma unroll
    for (int m = 32; m; m >>= 1) mx = fmaxf(mx, __shfl_xor(mx, m, 64));
    float s = 0.f;
#pragma unroll
    for (int i = 0; i < 32; ++i) { v[i] = __expf(v[i] - mx); s += v[i]; }
#pragma unroll
    for (int m = 32; m; m >>= 1) s += __shfl_xor(s, m, 64);
    const float rs = 1.0f / s;
#pragma unroll
    for (int i = 0; i < 4; ++i) {
        bf16x8_t t;
#pragma unroll
        for (int j = 0; j < 8; ++j) t[j] = (bf16_t)(v[i * 8 + j] * rs);
        *(bf16x8_t*)(r + (size_t)(lane + 64 * i) * 8) = t;
    }
}

// ---------------------------------------------------------------------------
// bf16 transpose: in [R][C] -> out [C][R], per-z batch. 64x64 LDS tile.
// ---------------------------------------------------------------------------
__global__ __launch_bounds__(512, 2)
void transpose_bf16(const bf16_t* __restrict__ in, bf16_t* __restrict__ out,
                    int R, int Ccols)
{
    __shared__ bf16_t s[64][65];
    const int tx = threadIdx.x, ty = threadIdx.y;   // block (64,8)
    const int x0 = blockIdx.x * 64, y0 = blockIdx.y * 64;
    in  += (size_t)blockIdx.z * R * Ccols;
    out += (size_t)blockIdx.z * R * Ccols;
#pragma unroll
    for (int r = 0; r < 8; ++r)
        s[ty + r * 8][tx] = in[(size_t)(y0 + ty + r * 8) * Ccols + x0 + tx];
    __syncthreads();
#pragma unroll
    for (int r = 0; r < 8; ++r)
        out[(size_t)(x0 + ty + r * 8) * R + y0 + tx] = s[tx][ty + r * 8];
}

// ---------------------------------------------------------------------------
// fp32 weight [K][N] -> bf16 transposed [N][K]. 32x32 LDS tile.
// ---------------------------------------------------------------------------
__global__ __launch_bounds__(256, 4)
void wconvT(const float* __restrict__ w, bf16_t* __restrict__ wt, int K, int N)
{
    __shared__ float s[32][33];
    const int tx = threadIdx.x, ty = threadIdx.y;   // block (32,8)
    const int n0 = blockIdx.x * 32, k0 = blockIdx.y * 32;
#pragma unroll
    for (int r = 0; r < 4; ++r)
        s[ty + r * 8][tx] = w[(size_t)(k0 + ty + r * 8) * N + n0 + tx];
    __syncthreads();
#pragma unroll
    for (int r = 0; r < 4; ++r)
        wt[(size_t)(n0 + ty + r * 8) * K + k0 + tx] = (bf16_t)s[tx][ty + r * 8];
}

// ---------------------------------------------------------------------------

extern "C" void kernel_launch(void* const* d_in, const int* in_sizes, int n_in,
                              void* d_out, int out_size, void* d_ws, size_t ws_size,
                              hipStream_t stream)
{
    const int B = 8, L1 = 2048, L2 = 2048, D1 = 1024, D2 = 768, E = 1024;
    const float scale = 0.03125f;  // E^-0.5

    const float* m1   = (const float*)d_in[0];
    const float* m2   = (const float*)d_in[1];
    const float* ln1g = (const float*)d_in[2];
    const float* ln1b = (const float*)d_in[3];
    const float* ln2g = (const float*)d_in[4];
    const float* ln2b = (const float*)d_in[5];
    const float* Wq   = (const float*)d_in[6];
    const float* bq   = (const float*)d_in[7];
    const float* Wk   = (const float*)d_in[8];
    const float* bk   = (const float*)d_in[9];
    const float* Wv   = (const float*)d_in[10];
    const float* bv   = (const float*)d_in[11];
    const float* Wo   = (const float*)d_in[12];
    const float* bo   = (const float*)d_in[13];
    float* out = (float*)d_out;

    bf16_t* ws = (bf16_t*)d_ws;
    size_t off = 0;
    auto alloc = [&](size_t n) { bf16_t* p = ws + off; off += n; return p; };
    bf16_t* WqT = alloc((size_t)E * D1);
    bf16_t* WkT = alloc((size_t)E * D2);
    bf16_t* WvT = alloc((size_t)E * D2);
    bf16_t* WoT = alloc((size_t)D1 * E);
    bf16_t* x1  = alloc((size_t)B * L1 * D1);
    bf16_t* x2  = alloc((size_t)B * L2 * D2);
    bf16_t* Qb  = alloc((size_t)B * L1 * E);
    bf16_t* Kb  = alloc((size_t)B * L2 * E);
    bf16_t* Vb  = alloc((size_t)B * L2 * E);
    bf16_t* VTb = alloc((size_t)B * E * L2);
    bf16_t* ctx = alloc((size_t)B * L1 * E);
    bf16_t* attn = ws + off;
    const bool batched = (off + (size_t)B * L1 * L2) * sizeof(bf16_t) <= ws_size;

    dim3 blk256(256);

    // 1. weights -> bf16 transposed
    wconvT<<<dim3(E / 32, D1 / 32), dim3(32, 8), 0, stream>>>(Wq, WqT, D1, E);
    wconvT<<<dim3(E / 32, D2 / 32), dim3(32, 8), 0, stream>>>(Wk, WkT, D2, E);
    wconvT<<<dim3(E / 32, D2 / 32), dim3(32, 8), 0, stream>>>(Wv, WvT, D2, E);
    wconvT<<<dim3(D1 / 32, E / 32), dim3(32, 8), 0, stream>>>(Wo, WoT, E, D1);

    // 2. layernorms -> bf16
    layernorm_k<4><<<dim3(B * L1 / 4), blk256, 0, stream>>>(m1, ln1g, ln1b, x1);
    layernorm_k<3><<<dim3(B * L2 / 4), blk256, 0, stream>>>(m2, ln2g, ln2b, x2);

    // 3. projections
    gemm_bt<bf16_t, true><<<dim3(E / 128, B * L1 / 128, 1), blk256, 0, stream>>>(
        x1, WqT, Qb, bq, B * L1, E, D1, 1.0f, 0, 0, 0);
    gemm_bt<bf16_t, true><<<dim3(E / 128, B * L2 / 128, 1), blk256, 0, stream>>>(
        x2, WkT, Kb, bk, B * L2, E, D2, 1.0f, 0, 0, 0);
    gemm_bt<bf16_t, true><<<dim3(E / 128, B * L2 / 128, 1), blk256, 0, stream>>>(
        x2, WvT, Vb, bv, B * L2, E, D2, 1.0f, 0, 0, 0);

    // 4. V -> V^T per batch
    transpose_bf16<<<dim3(E / 64, L2 / 64, B), dim3(64, 8), 0, stream>>>(
        Vb, VTb, L2, E);

    // 5. attention
    if (batched) {
        gemm_bt<bf16_t, false><<<dim3(L2 / 128, L1 / 128, B), blk256, 0, stream>>>(
            Qb, Kb, attn, nullptr, L1, L2, E, scale,
            (size_t)L1 * E, (size_t)L2 * E, (size_t)L1 * L2);
        softmax_rows<<<dim3(B * L1 / 4), blk256, 0, stream>>>(attn);
        gemm_bt<bf16_t, false><<<dim3(E / 128, L1 / 128, B), blk256, 0, stream>>>(
            attn, VTb, ctx, nullptr, L1, E, L2, 1.0f,
            (size_t)L1 * L2, (size_t)E * L2, (size_t)L1 * E);
    } else {
        for (int b = 0; b < B; ++b) {
            gemm_bt<bf16_t, false><<<dim3(L2 / 128, L1 / 128, 1), blk256, 0, stream>>>(
                Qb + (size_t)b * L1 * E, Kb + (size_t)b * L2 * E, attn, nullptr,
                L1, L2, E, scale, 0, 0, 0);
            softmax_rows<<<dim3(L1 / 4), blk256, 0, stream>>>(attn);
            gemm_bt<bf16_t, false><<<dim3(E / 128, L1 / 128, 1), blk256, 0, stream>>>(
                attn, VTb + (size_t)b * E * L2, ctx + (size_t)b * L1 * E, nullptr,
                L1, E, L2, 1.0f, 0, 0, 0);
        }
    }

    // 6. output projection -> fp32 d_out
    gemm_bt<float, true><<<dim3(D1 / 128, B * L1 / 128, 1), blk256, 0, stream>>>(
        ctx, WoT, out, bo, B * L1, D1, E, 1.0f, 0, 0, 0);
}

// Round 2
// 590.307 us; speedup vs baseline: 1.6121x; 1.6121x over previous
//
#include <hip/hip_runtime.h>
#include <hip/hip_bf16.h>

typedef __bf16 bf16_t;
typedef __bf16 bf16x4_t __attribute__((ext_vector_type(4)));
typedef __bf16 bf16x8_t __attribute__((ext_vector_type(8)));
typedef float f32x4_t __attribute__((ext_vector_type(4)));

typedef __attribute__((address_space(1))) void gvoid_t;
typedef __attribute__((address_space(3))) void svoid_t;

__device__ __forceinline__ void gload_lds16(const void* g, void* s) {
    // async global->LDS, 16B per lane; LDS dest = wave-uniform base + lane*16
    __builtin_amdgcn_global_load_lds((gvoid_t*)g, (svoid_t*)s, 16, 0, 0);
}

// ---------------------------------------------------------------------------
// m97-style GEMM: C[M,N] = scale * (A[M,K] @ Bt[N,K]^T) + bias
// 128x128 block tile, BK=32, 4 waves in 2x2, each wave 64x64 via 4x4 grid of
// 16x16x32 bf16 MFMAs. M%128==0, N%128==0, K%32==0 (all true here).
//
// LDS layout is XOR-swizzled at 16B-granule granularity to kill the 8-way
// ds_read_b128 bank conflicts of the naive [row][32] layout: physical chunk
// column = logical_chunk ^ ((row>>1)&3). global_load_lds forces slot =
// base + lane*16, so the swizzle is applied to the per-lane GLOBAL address
// on the staging side and to the LDS offset on the read side.
//
// STORE_T: write C transposed in per-batch segments (V -> V^T fused):
//   C[b][col][l] with b = row>>tshift, l = row & ((1<<tshift)-1).
// ---------------------------------------------------------------------------
template <typename CT, bool BIAS, bool STORE_T = false>
__global__ __launch_bounds__(256, 2)
void gemm_bt(const bf16_t* __restrict__ A, const bf16_t* __restrict__ Bt,
             CT* __restrict__ C, const float* __restrict__ bias,
             int M, int N, int K, float scale,
             size_t sA, size_t sB, size_t sC, int tshift)
{
    __shared__ bf16_t As[128 * 32];
    __shared__ bf16_t Bs[128 * 32];
    A  += (size_t)blockIdx.z * sA;
    Bt += (size_t)blockIdx.z * sB;
    C  += (size_t)blockIdx.z * sC;

    const int tid  = threadIdx.x;
    const int wave = tid >> 6;
    const int lane = tid & 63;
    const int m0 = blockIdx.y * 128;
    const int n0 = blockIdx.x * 128;

    // staging: slot granule c = tid + 256*j; row = c>>2; holds logical chunk
    // (c&3) ^ ((row>>1)&3)  [swizzle]
    const int c0 = tid, c1 = tid + 256;
    const int r0 = c0 >> 2, r1 = c1 >> 2;
    const int k0c = (((c0 & 3) ^ ((r0 >> 1) & 3))) * 8;
    const int k1c = (((c1 & 3) ^ ((r1 >> 1) & 3))) * 8;
    const bf16_t* ag0 = A  + (size_t)(m0 + r0) * K + k0c;
    const bf16_t* ag1 = A  + (size_t)(m0 + r1) * K + k1c;
    const bf16_t* bg0 = Bt + (size_t)(n0 + r0) * K + k0c;
    const bf16_t* bg1 = Bt + (size_t)(n0 + r1) * K + k1c;
    bf16_t* asb0 = As + (size_t)(wave * 64) * 8;        // + lane*16B implied
    bf16_t* asb1 = As + (size_t)(wave * 64 + 256) * 8;
    bf16_t* bsb0 = Bs + (size_t)(wave * 64) * 8;
    bf16_t* bsb1 = Bs + (size_t)(wave * 64 + 256) * 8;

    const int fr = lane & 15;          // fragment row (m or n)
    const int swz = (fr >> 1) & 3;     // row-swizzle term (i*16+wm don't affect it)
    const int fko = (((lane >> 4) ^ swz)) * 8;   // swizzled k offset (elems)
    const int wm = (wave >> 1) * 64;
    const int wn = (wave & 1) * 64;

    f32x4_t acc[4][4];
#pragma unroll
    for (int i = 0; i < 4; ++i)
#pragma unroll
        for (int j = 0; j < 4; ++j)
            acc[i][j] = (f32x4_t){0.f, 0.f, 0.f, 0.f};

    for (int kt = 0; kt < K; kt += 32) {
        gload_lds16(ag0, asb0);
        gload_lds16(ag1, asb1);
        gload_lds16(bg0, bsb0);
        gload_lds16(bg1, bsb1);
        ag0 += 32; ag1 += 32; bg0 += 32; bg1 += 32;
        __builtin_amdgcn_s_waitcnt(0);   // drain vmcnt before barrier
        __syncthreads();

        bf16x8_t af[4], bf[4];
#pragma unroll
        for (int i = 0; i < 4; ++i)
            af[i] = *(const bf16x8_t*)&As[(wm + i * 16 + fr) * 32 + fko];
#pragma unroll
        for (int j = 0; j < 4; ++j)
            bf[j] = *(const bf16x8_t*)&Bs[(wn + j * 16 + fr) * 32 + fko];
#pragma unroll
        for (int i = 0; i < 4; ++i)
#pragma unroll
            for (int j = 0; j < 4; ++j)
                acc[i][j] = __builtin_amdgcn_mfma_f32_16x16x32_bf16(
                    af[i], bf[j], acc[i][j], 0, 0, 0);
        __syncthreads();   // protect LDS before next stage
    }

    // C/D layout: col = lane&15, row = (lane>>4)*4 + r   [m89/m91 verified]
#pragma unroll
    for (int j = 0; j < 4; ++j) {
        const int col = n0 + wn + j * 16 + fr;
        const float bv = BIAS ? bias[col] : 0.0f;
#pragma unroll
        for (int i = 0; i < 4; ++i) {
            const int row = m0 + wm + i * 16 + (lane >> 4) * 4;
            f32x4_t v = acc[i][j];
            if constexpr (STORE_T) {
                // transposed: 4 consecutive l's of one VT row -> bf16x4
                const int b = row >> tshift;
                const int l = row & ((1 << tshift) - 1);
                bf16x4_t o;
#pragma unroll
                for (int r = 0; r < 4; ++r)
                    o[r] = (bf16_t)(v[r] * scale + bv);
                *(bf16x4_t*)((bf16_t*)C + ((size_t)b * N << tshift) +
                             ((size_t)col << tshift) + l) = o;
            } else {
#pragma unroll
                for (int r = 0; r < 4; ++r) {
                    float val = v[r] * scale + bv;
                    C[(size_t)(row + r) * N + col] = (CT)val;
                }
            }
        }
    }
}

// ---------------------------------------------------------------------------
// LayerNorm: one wave per row, D = NV*256 (NV float4 per lane). fp32 in,
// bf16 out.
// ---------------------------------------------------------------------------
template <int NV>
__global__ __launch_bounds__(256, 4)
void layernorm_k(const float* __restrict__ x, const float* __restrict__ g,
                 const float* __restrict__ b, bf16_t* __restrict__ y)
{
    const int D = NV * 256;
    const int wave = threadIdx.x >> 6, lane = threadIdx.x & 63;
    const size_t row = (size_t)blockIdx.x * 4 + wave;
    const float4* xr = (const float4*)(x + row * D);

    float4 v[NV];
    float s = 0.f, sq = 0.f;
#pragma unroll
    for (int i = 0; i < NV; ++i) {
        v[i] = xr[lane + 64 * i];
        s  += v[i].x + v[i].y + v[i].z + v[i].w;
        sq += v[i].x * v[i].x + v[i].y * v[i].y + v[i].z * v[i].z + v[i].w * v[i].w;
    }
#pragma unroll
    for (int m = 32; m; m >>= 1) {
        s  += __shfl_xor(s, m, 64);
        sq += __shfl_xor(sq, m, 64);
    }
    const float mean = s / D;
    const float rstd = rsqrtf(fmaxf(sq / D - mean * mean, 0.f) + 1e-5f);

#pragma unroll
    for (int i = 0; i < NV; ++i) {
        const int c4 = lane + 64 * i;
        float4 gg = ((const float4*)g)[c4];
        float4 bb = ((const float4*)b)[c4];
        bf16x4_t o;
        o[0] = (bf16_t)((v[i].x - mean) * rstd * gg.x + bb.x);
        o[1] = (bf16_t)((v[i].y - mean) * rstd * gg.y + bb.y);
        o[2] = (bf16_t)((v[i].z - mean) * rstd * gg.z + bb.z);
        o[3] = (bf16_t)((v[i].w - mean) * rstd * gg.w + bb.w);
        *(bf16x4_t*)(y + row * D + (size_t)c4 * 4) = o;
    }
}

// ---------------------------------------------------------------------------
// In-place row softmax over 2048 bf16 entries; one wave per row.
// ---------------------------------------------------------------------------
__global__ __launch_bounds__(256, 4)
void softmax_rows(bf16_t* __restrict__ a)
{
    const int wave = threadIdx.x >> 6, lane = threadIdx.x & 63;
    const size_t row = (size_t)blockIdx.x * 4 + wave;
    bf16_t* r = a + row * 2048;

    float v[32];
    float mx = -3.0e38f;
#pragma unroll
    for (int i = 0; i < 4; ++i) {
        bf16x8_t t = *(const bf16x8_t*)(r + (size_t)(lane + 64 * i) * 8);
#pragma unroll
        for (int j = 0; j < 8; ++j) {
            v[i * 8 + j] = (float)t[j];
            mx = fmaxf(mx, v[i * 8 + j]);
        }
    }
#pragma unroll
    for (int m = 32; m; m >>= 1) mx = fmaxf(mx, __shfl_xor(mx, m, 64));
    float s = 0.f;
#pragma unroll
    for (int i = 0; i < 32; ++i) { v[i] = __expf(v[i] - mx); s += v[i]; }
#pragma unroll
    for (int m = 32; m; m >>= 1) s += __shfl_xor(s, m, 64);
    const float rs = 1.0f / s;
#pragma unroll
    for (int i = 0; i < 4; ++i) {
        bf16x8_t t;
#pragma unroll
        for (int j = 0; j < 8; ++j) t[j] = (bf16_t)(v[i * 8 + j] * rs);
        *(bf16x8_t*)(r + (size_t)(lane + 64 * i) * 8) = t;
    }
}

// ---------------------------------------------------------------------------
// fp32 weight [K][N] -> bf16 transposed [N][K]. 32x32 LDS tile.
// ---------------------------------------------------------------------------
__global__ __launch_bounds__(256, 4)
void wconvT(const float* __restrict__ w, bf16_t* __restrict__ wt, int K, int N)
{
    __shared__ float s[32][33];
    const int tx = threadIdx.x, ty = threadIdx.y;   // block (32,8)
    const int n0 = blockIdx.x * 32, k0 = blockIdx.y * 32;
#pragma unroll
    for (int r = 0; r < 4; ++r)
        s[ty + r * 8][tx] = w[(size_t)(k0 + ty + r * 8) * N + n0 + tx];
    __syncthreads();
#pragma unroll
    for (int r = 0; r < 4; ++r)
        wt[(size_t)(n0 + ty + r * 8) * K + k0 + tx] = (bf16_t)s[tx][ty + r * 8];
}

// ---------------------------------------------------------------------------

extern "C" void kernel_launch(void* const* d_in, const int* in_sizes, int n_in,
                              void* d_out, int out_size, void* d_ws, size_t ws_size,
                              hipStream_t stream)
{
    const int B = 8, L1 = 2048, L2 = 2048, D1 = 1024, D2 = 768, E = 1024;
    const float scale = 0.03125f;  // E^-0.5
    const int tsh = 11;            // log2(L2)

    const float* m1   = (const float*)d_in[0];
    const float* m2   = (const float*)d_in[1];
    const float* ln1g = (const float*)d_in[2];
    const float* ln1b = (const float*)d_in[3];
    const float* ln2g = (const float*)d_in[4];
    const float* ln2b = (const float*)d_in[5];
    const float* Wq   = (const float*)d_in[6];
    const float* bq   = (const float*)d_in[7];
    const float* Wk   = (const float*)d_in[8];
    const float* bk   = (const float*)d_in[9];
    const float* Wv   = (const float*)d_in[10];
    const float* bv   = (const float*)d_in[11];
    const float* Wo   = (const float*)d_in[12];
    const float* bo   = (const float*)d_in[13];
    float* out = (float*)d_out;

    bf16_t* ws = (bf16_t*)d_ws;
    size_t off = 0;
    auto alloc = [&](size_t n) { bf16_t* p = ws + off; off += n; return p; };
    bf16_t* WqT = alloc((size_t)E * D1);
    bf16_t* WkT = alloc((size_t)E * D2);
    bf16_t* WvT = alloc((size_t)E * D2);
    bf16_t* WoT = alloc((size_t)D1 * E);
    bf16_t* x1  = alloc((size_t)B * L1 * D1);
    bf16_t* x2  = alloc((size_t)B * L2 * D2);
    bf16_t* Qb  = alloc((size_t)B * L1 * E);
    bf16_t* Kb  = alloc((size_t)B * L2 * E);
    bf16_t* VTb = alloc((size_t)B * E * L2);   // V^T, written directly by proj
    bf16_t* ctx = alloc((size_t)B * L1 * E);
    bf16_t* attn = ws + off;
    const bool batched = (off + (size_t)B * L1 * L2) * sizeof(bf16_t) <= ws_size;

    dim3 blk256(256);

    // 1. weights -> bf16 transposed
    wconvT<<<dim3(E / 32, D1 / 32), dim3(32, 8), 0, stream>>>(Wq, WqT, D1, E);
    wconvT<<<dim3(E / 32, D2 / 32), dim3(32, 8), 0, stream>>>(Wk, WkT, D2, E);
    wconvT<<<dim3(E / 32, D2 / 32), dim3(32, 8), 0, stream>>>(Wv, WvT, D2, E);
    wconvT<<<dim3(D1 / 32, E / 32), dim3(32, 8), 0, stream>>>(Wo, WoT, E, D1);

    // 2. layernorms -> bf16
    layernorm_k<4><<<dim3(B * L1 / 4), blk256, 0, stream>>>(m1, ln1g, ln1b, x1);
    layernorm_k<3><<<dim3(B * L2 / 4), blk256, 0, stream>>>(m2, ln2g, ln2b, x2);

    // 3. projections (V writes V^T directly via STORE_T epilogue)
    gemm_bt<bf16_t, true><<<dim3(E / 128, B * L1 / 128, 1), blk256, 0, stream>>>(
        x1, WqT, Qb, bq, B * L1, E, D1, 1.0f, 0, 0, 0, 0);
    gemm_bt<bf16_t, true><<<dim3(E / 128, B * L2 / 128, 1), blk256, 0, stream>>>(
        x2, WkT, Kb, bk, B * L2, E, D2, 1.0f, 0, 0, 0, 0);
    gemm_bt<bf16_t, true, true><<<dim3(E / 128, B * L2 / 128, 1), blk256, 0, stream>>>(
        x2, WvT, VTb, bv, B * L2, E, D2, 1.0f, 0, 0, 0, tsh);

    // 4. attention
    if (batched) {
        gemm_bt<bf16_t, false><<<dim3(L2 / 128, L1 / 128, B), blk256, 0, stream>>>(
            Qb, Kb, attn, nullptr, L1, L2, E, scale,
            (size_t)L1 * E, (size_t)L2 * E, (size_t)L1 * L2, 0);
        softmax_rows<<<dim3(B * L1 / 4), blk256, 0, stream>>>(attn);
        gemm_bt<bf16_t, false><<<dim3(E / 128, L1 / 128, B), blk256, 0, stream>>>(
            attn, VTb, ctx, nullptr, L1, E, L2, 1.0f,
            (size_t)L1 * L2, (size_t)E * L2, (size_t)L1 * E, 0);
    } else {
        for (int b = 0; b < B; ++b) {
            gemm_bt<bf16_t, false><<<dim3(L2 / 128, L1 / 128, 1), blk256, 0, stream>>>(
                Qb + (size_t)b * L1 * E, Kb + (size_t)b * L2 * E, attn, nullptr,
                L1, L2, E, scale, 0, 0, 0, 0);
            softmax_rows<<<dim3(L1 / 4), blk256, 0, stream>>>(attn);
            gemm_bt<bf16_t, false><<<dim3(E / 128, L1 / 128, 1), blk256, 0, stream>>>(
                attn, VTb + (size_t)b * E * L2, ctx + (size_t)b * L1 * E, nullptr,
                L1, E, L2, 1.0f, 0, 0, 0, 0);
        }
    }

    // 5. output projection -> fp32 d_out
    gemm_bt<float, true><<<dim3(D1 / 128, B * L1 / 128, 1), blk256, 0, stream>>>(
        ctx, WoT, out, bo, B * L1, D1, E, 1.0f, 0, 0, 0, 0);
}

// Round 3
// 541.593 us; speedup vs baseline: 1.7571x; 1.0899x over previous
//
#include <hip/hip_runtime.h>
#include <hip/hip_bf16.h>

typedef __bf16 bf16_t;
typedef __bf16 bf16x4_t __attribute__((ext_vector_type(4)));
typedef __bf16 bf16x8_t __attribute__((ext_vector_type(8)));
typedef float f32x4_t __attribute__((ext_vector_type(4)));

typedef __attribute__((address_space(1))) void gvoid_t;
typedef __attribute__((address_space(3))) void svoid_t;

__device__ __forceinline__ void gload_lds16(const void* g, void* s) {
    // async global->LDS, 16B per lane; LDS dest = wave-uniform base + lane*16
    __builtin_amdgcn_global_load_lds((gvoid_t*)g, (svoid_t*)s, 16, 0, 0);
}

// ---------------------------------------------------------------------------
// m97-style GEMM: C[M,N] = scale * (A[M,K] @ Bt[N,K]^T) + bias
// 128x128 block tile, BK=32, 4 waves in 2x2, each wave 64x64 via 4x4 grid of
// 16x16x32 bf16 MFMAs. M%128==0, N%128==0, K%32==0 (all true here).
//
// LDS 16B-granule XOR swizzle (R1: killed 4.2M bank conflicts -> 0):
// physical chunk col = logical_chunk ^ ((row>>1)&3), applied to the GLOBAL
// address on staging (global_load_lds forces slot = base + lane*16) and to
// the LDS offset on the read side.
//
// Tile swizzle (R2): HW dispatches consecutive linear blocks round-robin
// across 8 XCDs. Remap so each XCD owns a CONTIGUOUS tile range (for the
// batched attention GEMMs: exactly one batch per XCD), then walk bands of
// 8 by-rows column-major inside => L2 working set ~4-6 MB instead of the
// whole matrix. R2 baseline: FETCH 293 MB on QK^T vs 64 MB ideal.
//
// STORE_T: write C transposed in per-batch segments (V -> V^T fused):
//   C[b][col][l] with b = row>>tshift, l = row & ((1<<tshift)-1).
// ---------------------------------------------------------------------------
template <typename CT, bool BIAS, bool STORE_T = false>
__global__ __launch_bounds__(256, 2)
void gemm_bt(const bf16_t* __restrict__ A, const bf16_t* __restrict__ Bt,
             CT* __restrict__ C, const float* __restrict__ bias,
             int M, int N, int K, float scale,
             size_t sA, size_t sB, size_t sC, int tshift)
{
    __shared__ bf16_t As[128 * 32];
    __shared__ bf16_t Bs[128 * 32];

    // ---- tile swizzle -----------------------------------------------------
    const int nx = gridDim.x, ny = gridDim.y;
    const int nblk = nx * ny * (int)gridDim.z;
    int lin = blockIdx.x + nx * (blockIdx.y + ny * blockIdx.z);
    int tile = lin;
    if ((nblk & 7) == 0)                       // XCD-contiguous remap
        tile = (lin & 7) * (nblk >> 3) + (lin >> 3);
    const int per_z = nx * ny;
    const int bz = tile / per_z;
    int t = tile - bz * per_z;
    const int SB = 8;                          // band height (by-rows)
    const int band = t / (nx * SB);
    const int r = t - band * (nx * SB);
    const int h = min(SB, ny - band * SB);
    const int bx = r / h;
    const int by = band * SB + (r - bx * h);
    // -----------------------------------------------------------------------

    A  += (size_t)bz * sA;
    Bt += (size_t)bz * sB;
    C  += (size_t)bz * sC;

    const int tid  = threadIdx.x;
    const int wave = tid >> 6;
    const int lane = tid & 63;
    const int m0 = by * 128;
    const int n0 = bx * 128;

    // staging: slot granule c = tid + 256*j; row = c>>2; holds logical chunk
    // (c&3) ^ ((row>>1)&3)  [swizzle]
    const int c0 = tid, c1 = tid + 256;
    const int r0 = c0 >> 2, r1 = c1 >> 2;
    const int k0c = (((c0 & 3) ^ ((r0 >> 1) & 3))) * 8;
    const int k1c = (((c1 & 3) ^ ((r1 >> 1) & 3))) * 8;
    const bf16_t* ag0 = A  + (size_t)(m0 + r0) * K + k0c;
    const bf16_t* ag1 = A  + (size_t)(m0 + r1) * K + k1c;
    const bf16_t* bg0 = Bt + (size_t)(n0 + r0) * K + k0c;
    const bf16_t* bg1 = Bt + (size_t)(n0 + r1) * K + k1c;
    bf16_t* asb0 = As + (size_t)(wave * 64) * 8;        // + lane*16B implied
    bf16_t* asb1 = As + (size_t)(wave * 64 + 256) * 8;
    bf16_t* bsb0 = Bs + (size_t)(wave * 64) * 8;
    bf16_t* bsb1 = Bs + (size_t)(wave * 64 + 256) * 8;

    const int fr = lane & 15;          // fragment row (m or n)
    const int swz = (fr >> 1) & 3;     // row-swizzle term (i*16+wm don't affect it)
    const int fko = (((lane >> 4) ^ swz)) * 8;   // swizzled k offset (elems)
    const int wm = (wave >> 1) * 64;
    const int wn = (wave & 1) * 64;

    f32x4_t acc[4][4];
#pragma unroll
    for (int i = 0; i < 4; ++i)
#pragma unroll
        for (int j = 0; j < 4; ++j)
            acc[i][j] = (f32x4_t){0.f, 0.f, 0.f, 0.f};

    for (int kt = 0; kt < K; kt += 32) {
        gload_lds16(ag0, asb0);
        gload_lds16(ag1, asb1);
        gload_lds16(bg0, bsb0);
        gload_lds16(bg1, bsb1);
        ag0 += 32; ag1 += 32; bg0 += 32; bg1 += 32;
        __builtin_amdgcn_s_waitcnt(0);   // drain vmcnt before barrier
        __syncthreads();

        bf16x8_t af[4], bf[4];
#pragma unroll
        for (int i = 0; i < 4; ++i)
            af[i] = *(const bf16x8_t*)&As[(wm + i * 16 + fr) * 32 + fko];
#pragma unroll
        for (int j = 0; j < 4; ++j)
            bf[j] = *(const bf16x8_t*)&Bs[(wn + j * 16 + fr) * 32 + fko];
#pragma unroll
        for (int i = 0; i < 4; ++i)
#pragma unroll
            for (int j = 0; j < 4; ++j)
                acc[i][j] = __builtin_amdgcn_mfma_f32_16x16x32_bf16(
                    af[i], bf[j], acc[i][j], 0, 0, 0);
        __syncthreads();   // protect LDS before next stage
    }

    // C/D layout: col = lane&15, row = (lane>>4)*4 + r   [m89/m91 verified]
#pragma unroll
    for (int j = 0; j < 4; ++j) {
        const int col = n0 + wn + j * 16 + fr;
        const float bv = BIAS ? bias[col] : 0.0f;
#pragma unroll
        for (int i = 0; i < 4; ++i) {
            const int row = m0 + wm + i * 16 + (lane >> 4) * 4;
            f32x4_t v = acc[i][j];
            if constexpr (STORE_T) {
                // transposed: 4 consecutive l's of one VT row -> bf16x4
                const int b = row >> tshift;
                const int l = row & ((1 << tshift) - 1);
                bf16x4_t o;
#pragma unroll
                for (int rr = 0; rr < 4; ++rr)
                    o[rr] = (bf16_t)(v[rr] * scale + bv);
                *(bf16x4_t*)((bf16_t*)C + ((size_t)b * N << tshift) +
                             ((size_t)col << tshift) + l) = o;
            } else {
#pragma unroll
                for (int rr = 0; rr < 4; ++rr) {
                    float val = v[rr] * scale + bv;
                    C[(size_t)(row + rr) * N + col] = (CT)val;
                }
            }
        }
    }
}

// ---------------------------------------------------------------------------
// LayerNorm: one wave per row, D = NV*256 (NV float4 per lane). fp32 in,
// bf16 out.
// ---------------------------------------------------------------------------
template <int NV>
__global__ __launch_bounds__(256, 4)
void layernorm_k(const float* __restrict__ x, const float* __restrict__ g,
                 const float* __restrict__ b, bf16_t* __restrict__ y)
{
    const int D = NV * 256;
    const int wave = threadIdx.x >> 6, lane = threadIdx.x & 63;
    const size_t row = (size_t)blockIdx.x * 4 + wave;
    const float4* xr = (const float4*)(x + row * D);

    float4 v[NV];
    float s = 0.f, sq = 0.f;
#pragma unroll
    for (int i = 0; i < NV; ++i) {
        v[i] = xr[lane + 64 * i];
        s  += v[i].x + v[i].y + v[i].z + v[i].w;
        sq += v[i].x * v[i].x + v[i].y * v[i].y + v[i].z * v[i].z + v[i].w * v[i].w;
    }
#pragma unroll
    for (int m = 32; m; m >>= 1) {
        s  += __shfl_xor(s, m, 64);
        sq += __shfl_xor(sq, m, 64);
    }
    const float mean = s / D;
    const float rstd = rsqrtf(fmaxf(sq / D - mean * mean, 0.f) + 1e-5f);

#pragma unroll
    for (int i = 0; i < NV; ++i) {
        const int c4 = lane + 64 * i;
        float4 gg = ((const float4*)g)[c4];
        float4 bb = ((const float4*)b)[c4];
        bf16x4_t o;
        o[0] = (bf16_t)((v[i].x - mean) * rstd * gg.x + bb.x);
        o[1] = (bf16_t)((v[i].y - mean) * rstd * gg.y + bb.y);
        o[2] = (bf16_t)((v[i].z - mean) * rstd * gg.z + bb.z);
        o[3] = (bf16_t)((v[i].w - mean) * rstd * gg.w + bb.w);
        *(bf16x4_t*)(y + row * D + (size_t)c4 * 4) = o;
    }
}

// ---------------------------------------------------------------------------
// In-place row softmax over 2048 bf16 entries; one wave per row.
// ---------------------------------------------------------------------------
__global__ __launch_bounds__(256, 4)
void softmax_rows(bf16_t* __restrict__ a)
{
    const int wave = threadIdx.x >> 6, lane = threadIdx.x & 63;
    const size_t row = (size_t)blockIdx.x * 4 + wave;
    bf16_t* r = a + row * 2048;

    float v[32];
    float mx = -3.0e38f;
#pragma unroll
    for (int i = 0; i < 4; ++i) {
        bf16x8_t t = *(const bf16x8_t*)(r + (size_t)(lane + 64 * i) * 8);
#pragma unroll
        for (int j = 0; j < 8; ++j) {
            v[i * 8 + j] = (float)t[j];
            mx = fmaxf(mx, v[i * 8 + j]);
        }
    }
#pragma unroll
    for (int m = 32; m; m >>= 1) mx = fmaxf(mx, __shfl_xor(mx, m, 64));
    float s = 0.f;
#pragma unroll
    for (int i = 0; i < 32; ++i) { v[i] = __expf(v[i] - mx); s += v[i]; }
#pragma unroll
    for (int m = 32; m; m >>= 1) s += __shfl_xor(s, m, 64);
    const float rs = 1.0f / s;
#pragma unroll
    for (int i = 0; i < 4; ++i) {
        bf16x8_t t;
#pragma unroll
        for (int j = 0; j < 8; ++j) t[j] = (bf16_t)(v[i * 8 + j] * rs);
        *(bf16x8_t*)(r + (size_t)(lane + 64 * i) * 8) = t;
    }
}

// ---------------------------------------------------------------------------
// fp32 weight [K][N] -> bf16 transposed [N][K]. 32x32 LDS tile.
// ---------------------------------------------------------------------------
__global__ __launch_bounds__(256, 4)
void wconvT(const float* __restrict__ w, bf16_t* __restrict__ wt, int K, int N)
{
    __shared__ float s[32][33];
    const int tx = threadIdx.x, ty = threadIdx.y;   // block (32,8)
    const int n0 = blockIdx.x * 32, k0 = blockIdx.y * 32;
#pragma unroll
    for (int r = 0; r < 4; ++r)
        s[ty + r * 8][tx] = w[(size_t)(k0 + ty + r * 8) * N + n0 + tx];
    __syncthreads();
#pragma unroll
    for (int r = 0; r < 4; ++r)
        wt[(size_t)(n0 + ty + r * 8) * K + k0 + tx] = (bf16_t)s[tx][ty + r * 8];
}

// ---------------------------------------------------------------------------

extern "C" void kernel_launch(void* const* d_in, const int* in_sizes, int n_in,
                              void* d_out, int out_size, void* d_ws, size_t ws_size,
                              hipStream_t stream)
{
    const int B = 8, L1 = 2048, L2 = 2048, D1 = 1024, D2 = 768, E = 1024;
    const float scale = 0.03125f;  // E^-0.5
    const int tsh = 11;            // log2(L2)

    const float* m1   = (const float*)d_in[0];
    const float* m2   = (const float*)d_in[1];
    const float* ln1g = (const float*)d_in[2];
    const float* ln1b = (const float*)d_in[3];
    const float* ln2g = (const float*)d_in[4];
    const float* ln2b = (const float*)d_in[5];
    const float* Wq   = (const float*)d_in[6];
    const float* bq   = (const float*)d_in[7];
    const float* Wk   = (const float*)d_in[8];
    const float* bk   = (const float*)d_in[9];
    const float* Wv   = (const float*)d_in[10];
    const float* bv   = (const float*)d_in[11];
    const float* Wo   = (const float*)d_in[12];
    const float* bo   = (const float*)d_in[13];
    float* out = (float*)d_out;

    bf16_t* ws = (bf16_t*)d_ws;
    size_t off = 0;
    auto alloc = [&](size_t n) { bf16_t* p = ws + off; off += n; return p; };
    bf16_t* WqT = alloc((size_t)E * D1);
    bf16_t* WkT = alloc((size_t)E * D2);
    bf16_t* WvT = alloc((size_t)E * D2);
    bf16_t* WoT = alloc((size_t)D1 * E);
    bf16_t* x1  = alloc((size_t)B * L1 * D1);
    bf16_t* x2  = alloc((size_t)B * L2 * D2);
    bf16_t* Qb  = alloc((size_t)B * L1 * E);
    bf16_t* Kb  = alloc((size_t)B * L2 * E);
    bf16_t* VTb = alloc((size_t)B * E * L2);   // V^T, written directly by proj
    bf16_t* ctx = alloc((size_t)B * L1 * E);
    bf16_t* attn = ws + off;
    const bool batched = (off + (size_t)B * L1 * L2) * sizeof(bf16_t) <= ws_size;

    dim3 blk256(256);

    // 1. weights -> bf16 transposed
    wconvT<<<dim3(E / 32, D1 / 32), dim3(32, 8), 0, stream>>>(Wq, WqT, D1, E);
    wconvT<<<dim3(E / 32, D2 / 32), dim3(32, 8), 0, stream>>>(Wk, WkT, D2, E);
    wconvT<<<dim3(E / 32, D2 / 32), dim3(32, 8), 0, stream>>>(Wv, WvT, D2, E);
    wconvT<<<dim3(D1 / 32, E / 32), dim3(32, 8), 0, stream>>>(Wo, WoT, E, D1);

    // 2. layernorms -> bf16
    layernorm_k<4><<<dim3(B * L1 / 4), blk256, 0, stream>>>(m1, ln1g, ln1b, x1);
    layernorm_k<3><<<dim3(B * L2 / 4), blk256, 0, stream>>>(m2, ln2g, ln2b, x2);

    // 3. projections (V writes V^T directly via STORE_T epilogue)
    gemm_bt<bf16_t, true><<<dim3(E / 128, B * L1 / 128, 1), blk256, 0, stream>>>(
        x1, WqT, Qb, bq, B * L1, E, D1, 1.0f, 0, 0, 0, 0);
    gemm_bt<bf16_t, true><<<dim3(E / 128, B * L2 / 128, 1), blk256, 0, stream>>>(
        x2, WkT, Kb, bk, B * L2, E, D2, 1.0f, 0, 0, 0, 0);
    gemm_bt<bf16_t, true, true><<<dim3(E / 128, B * L2 / 128, 1), blk256, 0, stream>>>(
        x2, WvT, VTb, bv, B * L2, E, D2, 1.0f, 0, 0, 0, tsh);

    // 4. attention
    if (batched) {
        gemm_bt<bf16_t, false><<<dim3(L2 / 128, L1 / 128, B), blk256, 0, stream>>>(
            Qb, Kb, attn, nullptr, L1, L2, E, scale,
            (size_t)L1 * E, (size_t)L2 * E, (size_t)L1 * L2, 0);
        softmax_rows<<<dim3(B * L1 / 4), blk256, 0, stream>>>(attn);
        gemm_bt<bf16_t, false><<<dim3(E / 128, L1 / 128, B), blk256, 0, stream>>>(
            attn, VTb, ctx, nullptr, L1, E, L2, 1.0f,
            (size_t)L1 * L2, (size_t)E * L2, (size_t)L1 * E, 0);
    } else {
        for (int b = 0; b < B; ++b) {
            gemm_bt<bf16_t, false><<<dim3(L2 / 128, L1 / 128, 1), blk256, 0, stream>>>(
                Qb + (size_t)b * L1 * E, Kb + (size_t)b * L2 * E, attn, nullptr,
                L1, L2, E, scale, 0, 0, 0, 0);
            softmax_rows<<<dim3(L1 / 4), blk256, 0, stream>>>(attn);
            gemm_bt<bf16_t, false><<<dim3(E / 128, L1 / 128, 1), blk256, 0, stream>>>(
                attn, VTb + (size_t)b * E * L2, ctx + (size_t)b * L1 * E, nullptr,
                L1, E, L2, 1.0f, 0, 0, 0, 0);
        }
    }

    // 5. output projection -> fp32 d_out
    gemm_bt<float, true><<<dim3(D1 / 128, B * L1 / 128, 1), blk256, 0, stream>>>(
        ctx, WoT, out, bo, B * L1, D1, E, 1.0f, 0, 0, 0, 0);
}

// Round 4
// 540.233 us; speedup vs baseline: 1.7616x; 1.0025x over previous
//
#include <hip/hip_runtime.h>
#include <hip/hip_bf16.h>

typedef __bf16 bf16_t;
typedef __bf16 bf16x4_t __attribute__((ext_vector_type(4)));
typedef __bf16 bf16x8_t __attribute__((ext_vector_type(8)));
typedef float f32x4_t __attribute__((ext_vector_type(4)));
typedef float f32x16_t __attribute__((ext_vector_type(16)));

typedef __attribute__((address_space(1))) void gvoid_t;
typedef __attribute__((address_space(3))) void svoid_t;

__device__ __forceinline__ void gload_lds16(const void* g, void* s) {
    // async global->LDS, 16B per lane; LDS dest = wave-uniform base + lane*16
    __builtin_amdgcn_global_load_lds((gvoid_t*)g, (svoid_t*)s, 16, 0, 0);
}

// ---------------------------------------------------------------------------
// GEMM: C[M,N] = scale * (A[M,K] @ Bt[N,K]^T) + bias
// 128x128 block tile, BK=32, 4 waves in 2x2, each wave 64x64 via a 2x2 grid
// of 32x32 accs using v_mfma_f32_32x32x16_bf16 (R3: halves MFMA issue count
// vs 16x16x32; 32x32 ubench ceiling is +15%).
//
// LDS 16B-granule XOR swizzle (R1: killed 4.2M bank conflicts -> 0):
// physical chunk col = logical_chunk ^ ((row>>1)&3), applied to the GLOBAL
// address on staging (global_load_lds forces slot = base + lane*16) and to
// the LDS offset on the read side.
//
// Tile swizzle (R2: attn-GEMM FETCH 293->49 MB): XCD-contiguous remap +
// bands of 8 by-rows walked column-major => L2-resident working set.
//
// STORE_T: write C transposed in per-batch segments (V -> V^T fused):
//   C[b][col][l] with b = row>>tshift, l = row & ((1<<tshift)-1).
// ---------------------------------------------------------------------------
template <typename CT, bool BIAS, bool STORE_T = false>
__global__ __launch_bounds__(256, 2)
void gemm_bt(const bf16_t* __restrict__ A, const bf16_t* __restrict__ Bt,
             CT* __restrict__ C, const float* __restrict__ bias,
             int M, int N, int K, float scale,
             size_t sA, size_t sB, size_t sC, int tshift)
{
    __shared__ bf16_t As[128 * 32];
    __shared__ bf16_t Bs[128 * 32];

    // ---- tile swizzle -----------------------------------------------------
    const int nx = gridDim.x, ny = gridDim.y;
    const int nblk = nx * ny * (int)gridDim.z;
    int lin = blockIdx.x + nx * (blockIdx.y + ny * blockIdx.z);
    int tile = lin;
    if ((nblk & 7) == 0)                       // XCD-contiguous remap
        tile = (lin & 7) * (nblk >> 3) + (lin >> 3);
    const int per_z = nx * ny;
    const int bz = tile / per_z;
    int t = tile - bz * per_z;
    const int SB = 8;                          // band height (by-rows)
    const int band = t / (nx * SB);
    const int r = t - band * (nx * SB);
    const int h = min(SB, ny - band * SB);
    const int bx = r / h;
    const int by = band * SB + (r - bx * h);
    // -----------------------------------------------------------------------

    A  += (size_t)bz * sA;
    Bt += (size_t)bz * sB;
    C  += (size_t)bz * sC;

    const int tid  = threadIdx.x;
    const int wave = tid >> 6;
    const int lane = tid & 63;
    const int m0 = by * 128;
    const int n0 = bx * 128;

    // staging: slot granule c = tid + 256*j; row = c>>2; holds logical chunk
    // (c&3) ^ ((row>>1)&3)  [swizzle]
    const int c0 = tid, c1 = tid + 256;
    const int r0 = c0 >> 2, r1 = c1 >> 2;
    const int k0c = (((c0 & 3) ^ ((r0 >> 1) & 3))) * 8;
    const int k1c = (((c1 & 3) ^ ((r1 >> 1) & 3))) * 8;
    const bf16_t* ag0 = A  + (size_t)(m0 + r0) * K + k0c;
    const bf16_t* ag1 = A  + (size_t)(m0 + r1) * K + k1c;
    const bf16_t* bg0 = Bt + (size_t)(n0 + r0) * K + k0c;
    const bf16_t* bg1 = Bt + (size_t)(n0 + r1) * K + k1c;
    bf16_t* asb0 = As + (size_t)(wave * 64) * 8;        // + lane*16B implied
    bf16_t* asb1 = As + (size_t)(wave * 64 + 256) * 8;
    bf16_t* bsb0 = Bs + (size_t)(wave * 64) * 8;
    bf16_t* bsb1 = Bs + (size_t)(wave * 64 + 256) * 8;

    // 32x32x16 fragment addressing:
    //   A/B operand: m(or n) = lane&31, k = (lane>>5)*8 + j, j in [0,8)
    //   k-step kk in {0,1}: logical granule = 2*kk + (lane>>5)
    const int lr  = lane & 31;
    const int kh  = lane >> 5;
    const int swz = (lr >> 1) & 3;     // row-swizzle term (wm/mi*32 don't affect)
    const int wm = (wave >> 1) * 64;
    const int wn = (wave & 1) * 64;

    f32x16_t acc[2][2];
#pragma unroll
    for (int i = 0; i < 2; ++i)
#pragma unroll
        for (int j = 0; j < 2; ++j)
            acc[i][j] = (f32x16_t)(0.f);

    for (int kt = 0; kt < K; kt += 32) {
        gload_lds16(ag0, asb0);
        gload_lds16(ag1, asb1);
        gload_lds16(bg0, bsb0);
        gload_lds16(bg1, bsb1);
        ag0 += 32; ag1 += 32; bg0 += 32; bg1 += 32;
        __builtin_amdgcn_s_waitcnt(0);   // drain vmcnt before barrier
        __syncthreads();

        bf16x8_t af[2][2], bfr[2][2];
#pragma unroll
        for (int mi = 0; mi < 2; ++mi)
#pragma unroll
            for (int kk = 0; kk < 2; ++kk)
                af[mi][kk] = *(const bf16x8_t*)
                    &As[(wm + mi * 32 + lr) * 32 + ((2 * kk + kh) ^ swz) * 8];
#pragma unroll
        for (int nj = 0; nj < 2; ++nj)
#pragma unroll
            for (int kk = 0; kk < 2; ++kk)
                bfr[nj][kk] = *(const bf16x8_t*)
                    &Bs[(wn + nj * 32 + lr) * 32 + ((2 * kk + kh) ^ swz) * 8];
#pragma unroll
        for (int mi = 0; mi < 2; ++mi)
#pragma unroll
            for (int nj = 0; nj < 2; ++nj)
#pragma unroll
                for (int kk = 0; kk < 2; ++kk)
                    acc[mi][nj] = __builtin_amdgcn_mfma_f32_32x32x16_bf16(
                        af[mi][kk], bfr[nj][kk], acc[mi][nj], 0, 0, 0);
        __syncthreads();   // protect LDS before next stage
    }

    // 32x32 C/D layout: col = lane&31, row = (reg&3)+8*(reg>>2)+4*(lane>>5)
    // [m74/m101 verified]
#pragma unroll
    for (int nj = 0; nj < 2; ++nj) {
        const int col = n0 + wn + nj * 32 + lr;
        const float bv = BIAS ? bias[col] : 0.0f;
#pragma unroll
        for (int mi = 0; mi < 2; ++mi) {
            f32x16_t v = acc[mi][nj];
#pragma unroll
            for (int g = 0; g < 4; ++g) {
                const int row = m0 + wm + mi * 32 + 8 * g + 4 * kh;
                if constexpr (STORE_T) {
                    // transposed: 4 consecutive l's of one VT row -> bf16x4
                    const int b = row >> tshift;
                    const int l = row & ((1 << tshift) - 1);
                    bf16x4_t o;
#pragma unroll
                    for (int rr = 0; rr < 4; ++rr)
                        o[rr] = (bf16_t)(v[g * 4 + rr] * scale + bv);
                    *(bf16x4_t*)((bf16_t*)C + ((size_t)b * N << tshift) +
                                 ((size_t)col << tshift) + l) = o;
                } else {
#pragma unroll
                    for (int rr = 0; rr < 4; ++rr) {
                        float val = v[g * 4 + rr] * scale + bv;
                        C[(size_t)(row + rr) * N + col] = (CT)val;
                    }
                }
            }
        }
    }
}

// ---------------------------------------------------------------------------
// LayerNorm: one wave per row, D = NV*256 (NV float4 per lane). fp32 in,
// bf16 out.
// ---------------------------------------------------------------------------
template <int NV>
__global__ __launch_bounds__(256, 4)
void layernorm_k(const float* __restrict__ x, const float* __restrict__ g,
                 const float* __restrict__ b, bf16_t* __restrict__ y)
{
    const int D = NV * 256;
    const int wave = threadIdx.x >> 6, lane = threadIdx.x & 63;
    const size_t row = (size_t)blockIdx.x * 4 + wave;
    const float4* xr = (const float4*)(x + row * D);

    float4 v[NV];
    float s = 0.f, sq = 0.f;
#pragma unroll
    for (int i = 0; i < NV; ++i) {
        v[i] = xr[lane + 64 * i];
        s  += v[i].x + v[i].y + v[i].z + v[i].w;
        sq += v[i].x * v[i].x + v[i].y * v[i].y + v[i].z * v[i].z + v[i].w * v[i].w;
    }
#pragma unroll
    for (int m = 32; m; m >>= 1) {
        s  += __shfl_xor(s, m, 64);
        sq += __shfl_xor(sq, m, 64);
    }
    const float mean = s / D;
    const float rstd = rsqrtf(fmaxf(sq / D - mean * mean, 0.f) + 1e-5f);

#pragma unroll
    for (int i = 0; i < NV; ++i) {
        const int c4 = lane + 64 * i;
        float4 gg = ((const float4*)g)[c4];
        float4 bb = ((const float4*)b)[c4];
        bf16x4_t o;
        o[0] = (bf16_t)((v[i].x - mean) * rstd * gg.x + bb.x);
        o[1] = (bf16_t)((v[i].y - mean) * rstd * gg.y + bb.y);
        o[2] = (bf16_t)((v[i].z - mean) * rstd * gg.z + bb.z);
        o[3] = (bf16_t)((v[i].w - mean) * rstd * gg.w + bb.w);
        *(bf16x4_t*)(y + row * D + (size_t)c4 * 4) = o;
    }
}

// ---------------------------------------------------------------------------
// In-place row softmax over 2048 bf16 entries; one wave per row.
// ---------------------------------------------------------------------------
__global__ __launch_bounds__(256, 4)
void softmax_rows(bf16_t* __restrict__ a)
{
    const int wave = threadIdx.x >> 6, lane = threadIdx.x & 63;
    const size_t row = (size_t)blockIdx.x * 4 + wave;
    bf16_t* r = a + row * 2048;

    float v[32];
    float mx = -3.0e38f;
#pragma unroll
    for (int i = 0; i < 4; ++i) {
        bf16x8_t t = *(const bf16x8_t*)(r + (size_t)(lane + 64 * i) * 8);
#pragma unroll
        for (int j = 0; j < 8; ++j) {
            v[i * 8 + j] = (float)t[j];
            mx = fmaxf(mx, v[i * 8 + j]);
        }
    }
#pragma unroll
    for (int m = 32; m; m >>= 1) mx = fmaxf(mx, __shfl_xor(mx, m, 64));
    float s = 0.f;
#pragma unroll
    for (int i = 0; i < 32; ++i) { v[i] = __expf(v[i] - mx); s += v[i]; }
#pragma unroll
    for (int m = 32; m; m >>= 1) s += __shfl_xor(s, m, 64);
    const float rs = 1.0f / s;
#pragma unroll
    for (int i = 0; i < 4; ++i) {
        bf16x8_t t;
#pragma unroll
        for (int j = 0; j < 8; ++j) t[j] = (bf16_t)(v[i * 8 + j] * rs);
        *(bf16x8_t*)(r + (size_t)(lane + 64 * i) * 8) = t;
    }
}

// ---------------------------------------------------------------------------
// fp32 weight [K][N] -> bf16 transposed [N][K]. 32x32 LDS tile.
// ---------------------------------------------------------------------------
__global__ __launch_bounds__(256, 4)
void wconvT(const float* __restrict__ w, bf16_t* __restrict__ wt, int K, int N)
{
    __shared__ float s[32][33];
    const int tx = threadIdx.x, ty = threadIdx.y;   // block (32,8)
    const int n0 = blockIdx.x * 32, k0 = blockIdx.y * 32;
#pragma unroll
    for (int r = 0; r < 4; ++r)
        s[ty + r * 8][tx] = w[(size_t)(k0 + ty + r * 8) * N + n0 + tx];
    __syncthreads();
#pragma unroll
    for (int r = 0; r < 4; ++r)
        wt[(size_t)(n0 + ty + r * 8) * K + k0 + tx] = (bf16_t)s[tx][ty + r * 8];
}

// ---------------------------------------------------------------------------

extern "C" void kernel_launch(void* const* d_in, const int* in_sizes, int n_in,
                              void* d_out, int out_size, void* d_ws, size_t ws_size,
                              hipStream_t stream)
{
    const int B = 8, L1 = 2048, L2 = 2048, D1 = 1024, D2 = 768, E = 1024;
    const float scale = 0.03125f;  // E^-0.5
    const int tsh = 11;            // log2(L2)

    const float* m1   = (const float*)d_in[0];
    const float* m2   = (const float*)d_in[1];
    const float* ln1g = (const float*)d_in[2];
    const float* ln1b = (const float*)d_in[3];
    const float* ln2g = (const float*)d_in[4];
    const float* ln2b = (const float*)d_in[5];
    const float* Wq   = (const float*)d_in[6];
    const float* bq   = (const float*)d_in[7];
    const float* Wk   = (const float*)d_in[8];
    const float* bk   = (const float*)d_in[9];
    const float* Wv   = (const float*)d_in[10];
    const float* bv   = (const float*)d_in[11];
    const float* Wo   = (const float*)d_in[12];
    const float* bo   = (const float*)d_in[13];
    float* out = (float*)d_out;

    bf16_t* ws = (bf16_t*)d_ws;
    size_t off = 0;
    auto alloc = [&](size_t n) { bf16_t* p = ws + off; off += n; return p; };
    bf16_t* WqT = alloc((size_t)E * D1);
    bf16_t* WkT = alloc((size_t)E * D2);
    bf16_t* WvT = alloc((size_t)E * D2);
    bf16_t* WoT = alloc((size_t)D1 * E);
    bf16_t* x1  = alloc((size_t)B * L1 * D1);
    bf16_t* x2  = alloc((size_t)B * L2 * D2);
    bf16_t* Qb  = alloc((size_t)B * L1 * E);
    bf16_t* Kb  = alloc((size_t)B * L2 * E);
    bf16_t* VTb = alloc((size_t)B * E * L2);   // V^T, written directly by proj
    bf16_t* ctx = alloc((size_t)B * L1 * E);
    bf16_t* attn = ws + off;
    const bool batched = (off + (size_t)B * L1 * L2) * sizeof(bf16_t) <= ws_size;

    dim3 blk256(256);

    // 1. weights -> bf16 transposed
    wconvT<<<dim3(E / 32, D1 / 32), dim3(32, 8), 0, stream>>>(Wq, WqT, D1, E);
    wconvT<<<dim3(E / 32, D2 / 32), dim3(32, 8), 0, stream>>>(Wk, WkT, D2, E);
    wconvT<<<dim3(E / 32, D2 / 32), dim3(32, 8), 0, stream>>>(Wv, WvT, D2, E);
    wconvT<<<dim3(D1 / 32, E / 32), dim3(32, 8), 0, stream>>>(Wo, WoT, E, D1);

    // 2. layernorms -> bf16
    layernorm_k<4><<<dim3(B * L1 / 4), blk256, 0, stream>>>(m1, ln1g, ln1b, x1);
    layernorm_k<3><<<dim3(B * L2 / 4), blk256, 0, stream>>>(m2, ln2g, ln2b, x2);

    // 3. projections (V writes V^T directly via STORE_T epilogue)
    gemm_bt<bf16_t, true><<<dim3(E / 128, B * L1 / 128, 1), blk256, 0, stream>>>(
        x1, WqT, Qb, bq, B * L1, E, D1, 1.0f, 0, 0, 0, 0);
    gemm_bt<bf16_t, true><<<dim3(E / 128, B * L2 / 128, 1), blk256, 0, stream>>>(
        x2, WkT, Kb, bk, B * L2, E, D2, 1.0f, 0, 0, 0, 0);
    gemm_bt<bf16_t, true, true><<<dim3(E / 128, B * L2 / 128, 1), blk256, 0, stream>>>(
        x2, WvT, VTb, bv, B * L2, E, D2, 1.0f, 0, 0, 0, tsh);

    // 4. attention
    if (batched) {
        gemm_bt<bf16_t, false><<<dim3(L2 / 128, L1 / 128, B), blk256, 0, stream>>>(
            Qb, Kb, attn, nullptr, L1, L2, E, scale,
            (size_t)L1 * E, (size_t)L2 * E, (size_t)L1 * L2, 0);
        softmax_rows<<<dim3(B * L1 / 4), blk256, 0, stream>>>(attn);
        gemm_bt<bf16_t, false><<<dim3(E / 128, L1 / 128, B), blk256, 0, stream>>>(
            attn, VTb, ctx, nullptr, L1, E, L2, 1.0f,
            (size_t)L1 * L2, (size_t)E * L2, (size_t)L1 * E, 0);
    } else {
        for (int b = 0; b < B; ++b) {
            gemm_bt<bf16_t, false><<<dim3(L2 / 128, L1 / 128, 1), blk256, 0, stream>>>(
                Qb + (size_t)b * L1 * E, Kb + (size_t)b * L2 * E, attn, nullptr,
                L1, L2, E, scale, 0, 0, 0, 0);
            softmax_rows<<<dim3(L1 / 4), blk256, 0, stream>>>(attn);
            gemm_bt<bf16_t, false><<<dim3(E / 128, L1 / 128, 1), blk256, 0, stream>>>(
                attn, VTb + (size_t)b * E * L2, ctx + (size_t)b * L1 * E, nullptr,
                L1, E, L2, 1.0f, 0, 0, 0, 0);
        }
    }

    // 5. output projection -> fp32 d_out
    gemm_bt<float, true><<<dim3(D1 / 128, B * L1 / 128, 1), blk256, 0, stream>>>(
        ctx, WoT, out, bo, B * L1, D1, E, 1.0f, 0, 0, 0, 0);
}